// Round 7
// baseline (100.910 us; speedup 1.0000x reference)
//
#include <hip/hip_runtime.h>
#include <hip/hip_bf16.h>
#include <stdint.h>

#define NGRAPH 64
#define NMAX   512
#define NHEAD  4
#define BITMAP_WORDS (NGRAPH * NMAX * (NMAX / 32))   // 524,288 words
#define BITMAP_BYTES (BITMAP_WORDS * 4)              // 2 MiB

typedef float f4 __attribute__((ext_vector_type(4)));

// ---------- dispatch 1: zero bitmap + compute per-graph offsets ----------
__global__ void zero_prep_kernel(uint4* __restrict__ bm4,
                                 const int* __restrict__ nn,
                                 int* __restrict__ offs) {
    int tid = blockIdx.x * blockDim.x + threadIdx.x;   // 512 blocks * 256 = BITMAP_BYTES/16
    bm4[tid] = make_uint4(0u, 0u, 0u, 0u);
    if (blockIdx.x == 0 && threadIdx.x < 64) {
        int t = threadIdx.x;
        int v = nn[t];
        int x = v;
#pragma unroll
        for (int d = 1; d < 64; d <<= 1) {
            int y = __shfl_up(x, d, 64);
            if (t >= d) x += y;
        }
        offs[t] = x - v;      // exclusive prefix
    }
}

// ---------- dispatch 2: scan each edge exactly once ----------
__global__ void scan_kernel(const int* __restrict__ ei,
                            const int* __restrict__ offs,
                            uint32_t* __restrict__ bm,
                            int E, int epg) {
    int idx = blockIdx.x * blockDim.x + threadIdx.x;   // int4 index, E/4 total
    const int4* src4 = reinterpret_cast<const int4*>(ei);
    const int4* dst4 = reinterpret_cast<const int4*>(ei + E);
    int4 s = src4[idx];
    int4 d = dst4[idx];
    int e0 = idx << 2;
    int g  = e0 / epg;            // epg multiple of 4 -> same graph for all 4
    int off = offs[g];
    int base = g * (NMAX * NMAX / 32);
#pragma unroll
    for (int c = 0; c < 4; ++c) {
        int si = ((const int*)&s)[c] - off;
        int di = ((const int*)&d)[c] - off;
        atomicOr(&bm[base + si * 16 + (di >> 5)], 1u << (di & 31));
    }
}

// ---------- dispatch 3: pure fill-style write ----------
// Thread covers 64 B; wave covers 2 full rows (4 KB) as 4 contiguous
// 1 KB store instructions. No LDS; bits read as broadcast dwords from L2.
__global__ void write_kernel(const uint32_t* __restrict__ bm,
                             const int* __restrict__ nn,
                             const float* __restrict__ W,
                             f4* __restrict__ out4) {
    int tid  = blockIdx.x * blockDim.x + threadIdx.x;  // out_size/16 threads
    int lane = tid & 63;
    int R    = (tid >> 6) << 1;        // first of the wave's 2 global rows
    int i    = R & 511;                // wave-uniform
    int h    = (R >> 9) & 3;           // wave-uniform
    int b    = R >> 11;                // wave-uniform

    int nb = nn[b];
    float w0 = W[h];
    float w1 = W[4 + h];
    float w6 = W[24 + h];

    const uint32_t* row = bm + ((b << 9) + i) * 16;
    int wq = lane >> 3;                 // which word within half-row
    int sh = (lane & 7) << 2;           // 4 bits per lane
    uint32_t b00 = row[wq]      >> sh;  // row i,   j in [lane*4       .. )
    uint32_t b01 = row[8 + wq]  >> sh;  // row i,   j in [256+lane*4   .. )
    uint32_t b10 = row[16 + wq] >> sh;  // row i+1, first half
    uint32_t b11 = row[24 + wq] >> sh;  // row i+1, second half

    int j0 = lane << 2;
    f4 v0, v1, v2, v3;
    bool dv0 = (i < nb);
    bool dv1 = (i + 1 < nb);
#pragma unroll
    for (int k = 0; k < 4; ++k) {
        int j = j0 + k;
        float x0 = ((b00 >> k) & 1u) ? w1 : w6;
        if (dv0 && j == i) x0 = w0;
        v0[k] = x0;
        float x1 = ((b01 >> k) & 1u) ? w1 : w6;
        if (dv0 && (256 + j) == i) x1 = w0;
        v1[k] = x1;
        float x2 = ((b10 >> k) & 1u) ? w1 : w6;
        if (dv1 && j == i + 1) x2 = w0;
        v2[k] = x2;
        float x3 = ((b11 >> k) & 1u) ? w1 : w6;
        if (dv1 && (256 + j) == i + 1) x3 = w0;
        v3[k] = x3;
    }
    size_t base = (size_t)R << 7;       // row R * 128 f4
    __builtin_nontemporal_store(v0, &out4[base + lane]);
    __builtin_nontemporal_store(v1, &out4[base + 64 + lane]);
    __builtin_nontemporal_store(v2, &out4[base + 128 + lane]);
    __builtin_nontemporal_store(v3, &out4[base + 192 + lane]);
}

// ---------- fallback (ws too small): R6 fused kernel, no ws needed ----------
#define ROWS_PER_BLOCK 64
#define SLICES (NMAX / ROWS_PER_BLOCK)
#define NBLOCKS (NGRAPH * SLICES)

__global__ __launch_bounds__(256) void fused_structenc_kernel(
    const int* __restrict__ ei, const int* __restrict__ nn,
    const float* __restrict__ W, f4* __restrict__ out4, int E, int epg)
{
    int cpx = NBLOCKS >> 3;
    int wg  = (blockIdx.x & 7) * cpx + (blockIdx.x >> 3);
    int g     = wg >> 3;
    int slice = wg & 7;
    int r0    = slice * ROWS_PER_BLOCK;
    __shared__ uint32_t s_bits[ROWS_PER_BLOCK * (NMAX / 32)];
    __shared__ int s_off;
    int t = threadIdx.x;
#pragma unroll
    for (int z = 0; z < 4; ++z) s_bits[t + z * 256] = 0u;
    if (t < 64) {
        int v = nn[t]; int x = v;
#pragma unroll
        for (int d = 1; d < 64; d <<= 1) { int y = __shfl_up(x, d, 64); if (t >= d) x += y; }
        if (t == g) s_off = x - v;
    }
    __syncthreads();
    int off = s_off;
    int ebase = g * epg;
    const int4* src4 = reinterpret_cast<const int4*>(ei + ebase);
    int nvec = epg >> 2;
    for (int idx = t; idx < nvec; idx += 256) {
        int4 s = src4[idx];
        int e0 = ebase + (idx << 2);
#pragma unroll
        for (int c = 0; c < 4; ++c) {
            int si = ((const int*)&s)[c] - off;
            unsigned rr = (unsigned)(si - r0);
            if (rr < (unsigned)ROWS_PER_BLOCK) {
                int di = ei[E + e0 + c] - off;
                atomicOr(&s_bits[rr * 16 + (di >> 5)], 1u << (di & 31));
            }
        }
    }
    __syncthreads();
    int lane = t & 63;
    int h    = t >> 6;
    int nb   = nn[g];
    float w0 = W[h], w1 = W[4 + h], w6 = W[24 + h];
    size_t outbase = ((size_t)(g * NHEAD + h) * NMAX + r0) * (NMAX / 4);
    int j0 = lane << 2;
#pragma unroll 8
    for (int r = 0; r < ROWS_PER_BLOCK; ++r) {
        int i = r0 + r;
        uint32_t blo = s_bits[r * 16 +     (lane >> 3)] >> ((lane & 7) << 2);
        uint32_t bhi = s_bits[r * 16 + 8 + (lane >> 3)] >> ((lane & 7) << 2);
        f4 lo, hi;
        bool dv = (i < nb);
#pragma unroll
        for (int k2 = 0; k2 < 4; ++k2) {
            float v = ((blo >> k2) & 1u) ? w1 : w6;
            if (dv && (j0 + k2) == i) v = w0;
            lo[k2] = v;
            float v2 = ((bhi >> k2) & 1u) ? w1 : w6;
            if (dv && (256 + j0 + k2) == i) v2 = w0;
            hi[k2] = v2;
        }
        __builtin_nontemporal_store(lo, &out4[outbase + (size_t)r * 128 + lane]);
        __builtin_nontemporal_store(hi, &out4[outbase + (size_t)r * 128 + 64 + lane]);
    }
}

extern "C" void kernel_launch(void* const* d_in, const int* in_sizes, int n_in,
                              void* d_out, int out_size, void* d_ws, size_t ws_size,
                              hipStream_t stream) {
    const int*   ei = (const int*)d_in[0];
    const int*   nn = (const int*)d_in[2];
    const float* W  = (const float*)d_in[3];
    f4* out4 = (f4*)d_out;

    int E   = in_sizes[0] / 2;       // 1,048,576
    int epg = E / NGRAPH;            // 16,384

    size_t need = (size_t)BITMAP_BYTES + NGRAPH * sizeof(int);
    if (ws_size >= need) {
        uint32_t* bm = (uint32_t*)d_ws;
        int* offs = (int*)((char*)d_ws + BITMAP_BYTES);
        zero_prep_kernel<<<BITMAP_BYTES / 16 / 256, 256, 0, stream>>>((uint4*)d_ws, nn, offs);
        scan_kernel<<<(E / 4) / 256, 256, 0, stream>>>(ei, offs, bm, E, epg);
        int wthreads = out_size / 16;             // 4,194,304
        write_kernel<<<wthreads / 256, 256, 0, stream>>>(bm, nn, W, out4);
    } else {
        fused_structenc_kernel<<<NBLOCKS, 256, 0, stream>>>(ei, nn, W, out4, E, epg);
    }
}

// Round 8
// 63.132 us; speedup vs baseline: 1.5984x; 1.5984x over previous
//
#include <hip/hip_runtime.h>
#include <hip/hip_bf16.h>
#include <stdint.h>

#define NGRAPH 64
#define NMAX   512
#define NHEAD  4
#define WPR    (NMAX / 32)                    // 16 bitmap words per row
#define BM_WORDS (NGRAPH * NMAX * WPR)        // 524,288
#define BM_BYTES (BM_WORDS * 4)               // 2 MiB

typedef float f4 __attribute__((ext_vector_type(4)));

// ---------- dispatch A: LDS scan per (graph, 64-row slice) -> dump to global bitmap ----------
#define ROWS_A   64
#define SLICES_A (NMAX / ROWS_A)              // 8
#define NBLK_A   (NGRAPH * SLICES_A)          // 512

__global__ __launch_bounds__(256) void scan_dump_kernel(
    const int* __restrict__ ei,               // [2, E]
    const int* __restrict__ nn,               // [64]
    uint32_t* __restrict__ bm,                // [64][512][16] words
    int E, int epg)
{
    // XCD swizzle: all 8 slices of a graph on one XCD -> edge list L2-hit
    int cpx = NBLK_A >> 3;                    // 64
    int wg  = (blockIdx.x & 7) * cpx + (blockIdx.x >> 3);
    int g     = wg >> 3;
    int slice = wg & 7;
    int r0    = slice * ROWS_A;

    __shared__ uint32_t s_bits[ROWS_A * WPR]; // 4 KB
    __shared__ int s_off;
    int t = threadIdx.x;
#pragma unroll
    for (int z = 0; z < 4; ++z) s_bits[t + z * 256] = 0u;
    if (t < 64) {
        int v = nn[t]; int x = v;
#pragma unroll
        for (int d = 1; d < 64; d <<= 1) { int y = __shfl_up(x, d, 64); if (t >= d) x += y; }
        if (t == g) s_off = x - v;
    }
    __syncthreads();

    int off   = s_off;
    int ebase = g * epg;
    const int4* src4 = reinterpret_cast<const int4*>(ei + ebase);
    int nvec = epg >> 2;                      // 4096 -> 16 iters/thread
    for (int idx = t; idx < nvec; idx += 256) {
        int4 s = src4[idx];
        int e0 = ebase + (idx << 2);
#pragma unroll
        for (int c = 0; c < 4; ++c) {
            int si = ((const int*)&s)[c] - off;
            unsigned rr = (unsigned)(si - r0);
            if (rr < (unsigned)ROWS_A) {
                int di = ei[E + e0 + c] - off;
                atomicOr(&s_bits[rr * WPR + (di >> 5)], 1u << (di & 31));
            }
        }
    }
    __syncthreads();

    // dump the slice's 1024 words: one uint4 per thread, fully coalesced
    uint4 vd;
    vd.x = s_bits[t * 4 + 0]; vd.y = s_bits[t * 4 + 1];
    vd.z = s_bits[t * 4 + 2]; vd.w = s_bits[t * 4 + 3];
    reinterpret_cast<uint4*>(bm + g * (NMAX * WPR) + r0 * WPR)[t] = vd;
}

// ---------- dispatch B: pure fill-style write ----------
// Wave writes 2 full rows (4 KB) as 4 contiguous 1 KB nt-store instructions.
// No LDS, minimal VGPRs; bits come as coalesced dword loads from the bitmap.
__global__ __launch_bounds__(256) void write_kernel(
    const uint32_t* __restrict__ bm,
    const int* __restrict__ nn,
    const float* __restrict__ W,
    f4* __restrict__ out4)
{
    int tid  = blockIdx.x * blockDim.x + threadIdx.x;  // out_size/16 threads
    int lane = tid & 63;
    int R    = (tid >> 6) << 1;        // first of the wave's 2 global rows
    int i    = R & 511;                // wave-uniform
    int h    = (R >> 9) & 3;           // wave-uniform
    int b    = R >> 11;                // wave-uniform

    int nb = nn[b];
    float w0 = W[h];
    float w1 = W[4 + h];
    float w6 = W[24 + h];

    const uint32_t* row = bm + ((b << 9) + i) * WPR;
    int wq = lane >> 3;
    int sh = (lane & 7) << 2;
    uint32_t b00 = row[wq]      >> sh;  // row i,   j in [0,256)
    uint32_t b01 = row[8 + wq]  >> sh;  // row i,   j in [256,512)
    uint32_t b10 = row[16 + wq] >> sh;  // row i+1, j in [0,256)
    uint32_t b11 = row[24 + wq] >> sh;  // row i+1, j in [256,512)

    int j0 = lane << 2;
    f4 v0, v1, v2, v3;
    bool dv0 = (i < nb);
    bool dv1 = (i + 1 < nb);
#pragma unroll
    for (int k = 0; k < 4; ++k) {
        int j = j0 + k;
        float x0 = ((b00 >> k) & 1u) ? w1 : w6;
        if (dv0 && j == i) x0 = w0;
        v0[k] = x0;
        float x1 = ((b01 >> k) & 1u) ? w1 : w6;
        if (dv0 && (256 + j) == i) x1 = w0;
        v1[k] = x1;
        float x2 = ((b10 >> k) & 1u) ? w1 : w6;
        if (dv1 && j == i + 1) x2 = w0;
        v2[k] = x2;
        float x3 = ((b11 >> k) & 1u) ? w1 : w6;
        if (dv1 && (256 + j) == i + 1) x3 = w0;
        v3[k] = x3;
    }
    size_t base = (size_t)R << 7;       // row R * 128 f4
    __builtin_nontemporal_store(v0, &out4[base + lane]);
    __builtin_nontemporal_store(v1, &out4[base + 64 + lane]);
    __builtin_nontemporal_store(v2, &out4[base + 128 + lane]);
    __builtin_nontemporal_store(v3, &out4[base + 192 + lane]);
}

// ---------- fallback (ws too small): R6 fused kernel ----------
#define ROWS_PER_BLOCK 64
#define SLICES (NMAX / ROWS_PER_BLOCK)
#define NBLOCKS (NGRAPH * SLICES)

__global__ __launch_bounds__(256) void fused_structenc_kernel(
    const int* __restrict__ ei, const int* __restrict__ nn,
    const float* __restrict__ W, f4* __restrict__ out4, int E, int epg)
{
    int cpx = NBLOCKS >> 3;
    int wg  = (blockIdx.x & 7) * cpx + (blockIdx.x >> 3);
    int g     = wg >> 3;
    int slice = wg & 7;
    int r0    = slice * ROWS_PER_BLOCK;
    __shared__ uint32_t s_bits[ROWS_PER_BLOCK * WPR];
    __shared__ int s_off;
    int t = threadIdx.x;
#pragma unroll
    for (int z = 0; z < 4; ++z) s_bits[t + z * 256] = 0u;
    if (t < 64) {
        int v = nn[t]; int x = v;
#pragma unroll
        for (int d = 1; d < 64; d <<= 1) { int y = __shfl_up(x, d, 64); if (t >= d) x += y; }
        if (t == g) s_off = x - v;
    }
    __syncthreads();
    int off = s_off;
    int ebase = g * epg;
    const int4* src4 = reinterpret_cast<const int4*>(ei + ebase);
    int nvec = epg >> 2;
    for (int idx = t; idx < nvec; idx += 256) {
        int4 s = src4[idx];
        int e0 = ebase + (idx << 2);
#pragma unroll
        for (int c = 0; c < 4; ++c) {
            int si = ((const int*)&s)[c] - off;
            unsigned rr = (unsigned)(si - r0);
            if (rr < (unsigned)ROWS_PER_BLOCK) {
                int di = ei[E + e0 + c] - off;
                atomicOr(&s_bits[rr * WPR + (di >> 5)], 1u << (di & 31));
            }
        }
    }
    __syncthreads();
    int lane = t & 63;
    int h    = t >> 6;
    int nb   = nn[g];
    float w0 = W[h], w1 = W[4 + h], w6 = W[24 + h];
    size_t outbase = ((size_t)(g * NHEAD + h) * NMAX + r0) * (NMAX / 4);
    int j0 = lane << 2;
#pragma unroll 8
    for (int r = 0; r < ROWS_PER_BLOCK; ++r) {
        int i = r0 + r;
        uint32_t blo = s_bits[r * WPR +     (lane >> 3)] >> ((lane & 7) << 2);
        uint32_t bhi = s_bits[r * WPR + 8 + (lane >> 3)] >> ((lane & 7) << 2);
        f4 lo, hi;
        bool dv = (i < nb);
#pragma unroll
        for (int k2 = 0; k2 < 4; ++k2) {
            float v = ((blo >> k2) & 1u) ? w1 : w6;
            if (dv && (j0 + k2) == i) v = w0;
            lo[k2] = v;
            float v2 = ((bhi >> k2) & 1u) ? w1 : w6;
            if (dv && (256 + j0 + k2) == i) v2 = w0;
            hi[k2] = v2;
        }
        __builtin_nontemporal_store(lo, &out4[outbase + (size_t)r * 128 + lane]);
        __builtin_nontemporal_store(hi, &out4[outbase + (size_t)r * 128 + 64 + lane]);
    }
}

extern "C" void kernel_launch(void* const* d_in, const int* in_sizes, int n_in,
                              void* d_out, int out_size, void* d_ws, size_t ws_size,
                              hipStream_t stream) {
    const int*   ei = (const int*)d_in[0];
    const int*   nn = (const int*)d_in[2];
    const float* W  = (const float*)d_in[3];
    f4* out4 = (f4*)d_out;

    int E   = in_sizes[0] / 2;       // 1,048,576
    int epg = E / NGRAPH;            // 16,384

    if (ws_size >= (size_t)BM_BYTES) {
        uint32_t* bm = (uint32_t*)d_ws;
        scan_dump_kernel<<<NBLK_A, 256, 0, stream>>>(ei, nn, bm, E, epg);
        int wthreads = out_size / 16;             // 4,194,304
        write_kernel<<<wthreads / 256, 256, 0, stream>>>(bm, nn, W, out4);
    } else {
        fused_structenc_kernel<<<NBLOCKS, 256, 0, stream>>>(ei, nn, W, out4, E, epg);
    }
}